// Round 6
// baseline (204.119 us; speedup 1.0000x reference)
//
#include <hip/hip_runtime.h>
#include <hip/hip_cooperative_groups.h>
#include <math.h>

namespace cg = cooperative_groups;

#define N_TOK 40
#define N1    41      // N_TOK + 1
#define BS    8
#define DD    256     // D
#define HH    256     // H
#define NTRI  10660   // C(41,3)
#define NTASK (NTRI * BS)  // 85280
#define ROWF  (BS * N1 * HH)  // 83968 floats per [b][t][h] array
#define MNEG  (-1e38f)
#define GRID  256     // co-resident: 1 block/CU
#define BLK   256

// B packed upper-triangular per b: cell (i,j), j>i, at tri_base(i) + (j-i-1).
__device__ __forceinline__ int tri_base(int i) { return (i * (81 - i)) >> 1; }
#define BIDX(i, j) (tri_base(i) + ((j) - (i) - 1))

// per-b element offset of step-W's S chunk, (w,i,j') enumeration
constexpr int soff(int W) {
    int s = 0;
    for (int v = 2; v < W; ++v) s += (N1 - v) * (v - 1);
    return s;
}
// lanes per cell: pow2, m*T <= 256, T <= 16 -> CH <= 4, butterfly <= 4 rounds
constexpr int pick_T(int m, int nj) {
    int T = 1;
    while (T < 16 && m * (T * 2) <= BLK && T < nj) T *= 2;
    return T;
}

template<int W>
__device__ __forceinline__ void dp_step(float* __restrict__ Btri,
                                        const float* __restrict__ Sl, int tid)
{
    constexpr int m    = N1 - W;
    constexpr int nj   = W - 1;
    constexpr int T    = pick_T(m, nj);
    constexpr int CH   = (nj + T - 1) / T;
    constexpr int base = soff(W);

    if (tid < m * T) {
        const int i = tid / T;
        const int h = tid % T;
        const int k = i + W;

        float g[CH];
        #pragma unroll
        for (int q = 0; q < CH; ++q) {
            int jp = h + q * T;                        // strided: lanes -> consecutive addrs
            bool live = (q < CH - 1) || (jp < nj);     // compile-time true except last q
            int jj = live ? jp : 0;
            float v = Sl[base + i * nj + jj]
                    + Btri[BIDX(i, i + 1 + jj)]
                    + Btri[BIDX(i + 1 + jj, k)];
            g[q] = live ? v : MNEG;
        }
        // local tree LSE (<=4 elements)
        float mx = g[0];
        #pragma unroll
        for (int q = 1; q < CH; ++q) mx = fmaxf(mx, g[q]);
        float s = 0.f;
        #pragma unroll
        for (int q = 0; q < CH; ++q) s += __expf(g[q] - mx);
        // in-wave fused online-LSE butterfly over T lanes (<=4 rounds).
        // Fully-dead lanes (mx==MNEG) are annihilated: exp(MNEG - real) == 0,
        // and lane h==0 is always live.
        #pragma unroll
        for (int d = 1; d < T; d <<= 1) {
            float mo = __shfl_xor(mx, d);
            float so = __shfl_xor(s, d);
            float nm = fmaxf(mx, mo);
            s = s * __expf(mx - nm) + so * __expf(mo - nm);
            mx = nm;
        }
        if (h == 0)
            Btri[BIDX(i, k)] = mx + __logf(s);   // width-W entry: never read at step W
    }
    __syncthreads();   // one 4-wave barrier per step
}

template<int W>
__device__ __forceinline__ void dp_from(float* __restrict__ Btri,
                                        const float* __restrict__ Sl, int tid)
{
    dp_step<W>(Btri, Sl, tid);
    if constexpr (W + 1 <= N_TOK) dp_from<W + 1>(Btri, Sl, tid);
}

// ---------------- fused single-dispatch kernel ----------------
__global__ __launch_bounds__(BLK) void k_fused(
    const float* __restrict__ enc, const float* __restrict__ W1,
    const float* __restrict__ b1,  const float* __restrict__ W2,
    const float* __restrict__ b2,  const int* __restrict__ lengths,
    float* __restrict__ P, float* __restrict__ Qb, float* __restrict__ Dd,
    float* __restrict__ S, float* __restrict__ out)
{
    __shared__ __align__(16) float smem[NTRI + 820];   // 45,920 B, phase-overlapped
    const int tid = threadIdx.x;
    const int bid = blockIdx.x;
    cg::grid_group grid = cg::this_grid();

    // ======== Phase 1: projections P = enc@W1L, Qb = enc@W1R + b1, D = P - Q
    if (bid < N1) {
        const int t = bid;       // 0..40
        const int h = tid;       // 0..255
        float (*e)[DD] = (float (*)[DD])smem;
        #pragma unroll
        for (int b = 0; b < BS; ++b)
            e[b][h] = enc[(t * BS + b) * DD + h];
        __syncthreads();

        float accP[BS], accQ[BS];
        #pragma unroll
        for (int b = 0; b < BS; ++b) { accP[b] = 0.f; accQ[b] = 0.f; }

        for (int d = 0; d < DD; ++d) {
            float wp = W1[d * HH + h];
            float wq = W1[(DD + d) * HH + h];
            #pragma unroll
            for (int b = 0; b < BS; ++b) {
                float ev = e[b][d];
                accP[b] = fmaf(ev, wp, accP[b]);
                accQ[b] = fmaf(ev, wq, accQ[b]);
            }
        }
        float bb = b1[h];
        #pragma unroll
        for (int b = 0; b < BS; ++b) {
            int idx = ((b * N1) + t) * HH + h;
            P[idx]  = accP[b];
            Qb[idx] = accQ[b] + bb;
            Dd[idx] = accP[b] - accQ[b];
        }
    }
    grid.sync();

    // ======== Phase 2: per-triple scores, 16 lanes per (tri,b) task, grid-strided.
    // Chunk stride 65536 and tail 53760 are both multiples of 64 -> 16-lane task
    // groups never straddle a wave and are fully live or fully dead.
    for (int gt = bid * BLK + tid; gt < NTASK * 16; gt += GRID * BLK) {
        int task = gt >> 4;
        int t    = gt & 15;
        int b   = task / NTRI;
        int tri = task - b * NTRI;

        // decode tri -> (w, i, j') in (w,i,j') enumeration order
        int rem = tri, w = 2;
        while (true) {
            int cnt = (N1 - w) * (w - 1);
            if (rem < cnt) break;
            rem -= cnt; ++w;
        }
        int nj = w - 1;
        int i  = rem / nj;
        int jp = rem - i * nj;
        int j  = i + 1 + jp;
        int k  = i + w;

        const float4* Pr  = (const float4*)(P  + ((b * N1 + i) << 8)) + t * 4;
        const float4* Qr  = (const float4*)(Qb + ((b * N1 + k) << 8)) + t * 4;
        const float4* Dr  = (const float4*)(Dd + ((b * N1 + j) << 8)) + t * 4;
        const float4* W2r = (const float4*)(W2) + t * 8;   // W2[h][2]

        float s0 = 0.f, s1 = 0.f;
        #pragma unroll
        for (int q = 0; q < 4; ++q) {
            float4 p = Pr[q], qq = Qr[q], dd = Dr[q];
            float4 wa = W2r[q * 2], wb = W2r[q * 2 + 1];
            float r0 = fmaxf(dd.x + qq.x - p.x, 0.f);
            float r1 = fmaxf(dd.y + qq.y - p.y, 0.f);
            float r2 = fmaxf(dd.z + qq.z - p.z, 0.f);
            float r3 = fmaxf(dd.w + qq.w - p.w, 0.f);
            s0 = fmaf(r0, wa.x, s0); s1 = fmaf(r0, wa.y, s1);
            s0 = fmaf(r1, wa.z, s0); s1 = fmaf(r1, wa.w, s1);
            s0 = fmaf(r2, wb.x, s0); s1 = fmaf(r2, wb.y, s1);
            s0 = fmaf(r3, wb.z, s0); s1 = fmaf(r3, wb.w, s1);
        }
        #pragma unroll
        for (int d = 1; d < 16; d <<= 1) {
            s0 += __shfl_xor(s0, d);
            s1 += __shfl_xor(s1, d);
        }
        if (t == 0) {
            float S0 = s0 + b2[0], S1 = s1 + b2[1];
            S[b * NTRI + tri] = fmaxf(S0, S1) + log1pf(__expf(-fabsf(S0 - S1)));
        }
    }
    grid.sync();

    // ======== Phase 3: per-batch DP (blocks 0..7), 4 waves each
    if (bid < BS) {
        float* Sl   = smem;          // 42640 B
        float* Btri = smem + NTRI;   // 3280 B (offset 16B-aligned)
        const int b = bid;

        // stage all of S[b]: NTRI/4 = 2665 float4s (exact), 16B-aligned per b
        const float4* src = (const float4*)(S + b * NTRI);
        float4* dst = (float4*)Sl;
        for (int x = tid; x < NTRI / 4; x += BLK) dst[x] = src[x];
        // width-1 diagonal = 0 (only read entries not computed in the loop)
        if (tid < N_TOK) Btri[tri_base(tid)] = 0.f;
        __syncthreads();

        dp_from<2>(Btri, Sl, tid);

        if (tid == 0) {
            int L = lengths[b];
            out[b] = Btri[BIDX(0, L)];
        }
    }
}

extern "C" void kernel_launch(void* const* d_in, const int* in_sizes, int n_in,
                              void* d_out, int out_size, void* d_ws, size_t ws_size,
                              hipStream_t stream)
{
    const float* enc = (const float*)d_in[0];
    const float* W1  = (const float*)d_in[1];
    const float* b1  = (const float*)d_in[2];
    const float* W2  = (const float*)d_in[3];
    const float* b2  = (const float*)d_in[4];
    const int* lengths = (const int*)d_in[5];

    float* ws = (float*)d_ws;
    float* P  = ws;
    float* Qb = ws + ROWF;
    float* Dd = ws + 2 * ROWF;
    float* S  = ws + 3 * ROWF;   // NTASK floats; total ws use ~1.35 MB
    float* out = (float*)d_out;

    void* args[] = {
        (void*)&enc, (void*)&W1, (void*)&b1, (void*)&W2, (void*)&b2,
        (void*)&lengths, (void*)&P, (void*)&Qb, (void*)&Dd, (void*)&S, (void*)&out
    };
    hipLaunchCooperativeKernel((const void*)k_fused, dim3(GRID), dim3(BLK),
                               args, 0, stream);
}

// Round 7
// 142.490 us; speedup vs baseline: 1.4325x; 1.4325x over previous
//
#include <hip/hip_runtime.h>
#include <math.h>

#define N_TOK 40
#define N1    41      // N_TOK + 1
#define BS    8
#define DD    256     // D
#define HH    256     // H
#define NTRI  10660   // C(41,3)
#define NTASK (NTRI * BS)  // 85280
#define ROWF  (BS * N1 * HH)  // 83968 floats per [b][t][h] array
#define MNEG  (-1e38f)
#define DPB   256     // DP block: 4 waves

// ---------------- Kernel 1: projections P = enc@W1L, Qb = enc@W1R + b1, D = P - Q
__global__ __launch_bounds__(256) void k_proj(
    const float* __restrict__ enc, const float* __restrict__ W1,
    const float* __restrict__ b1,
    float* __restrict__ P, float* __restrict__ Qb, float* __restrict__ Dd)
{
    const int t = blockIdx.x;    // 0..40
    const int h = threadIdx.x;   // 0..255
    __shared__ float e[BS][DD];
    #pragma unroll
    for (int b = 0; b < BS; ++b)
        e[b][h] = enc[(t * BS + b) * DD + h];
    __syncthreads();

    float accP[BS], accQ[BS];
    #pragma unroll
    for (int b = 0; b < BS; ++b) { accP[b] = 0.f; accQ[b] = 0.f; }

    for (int d = 0; d < DD; ++d) {
        float wp = W1[d * HH + h];
        float wq = W1[(DD + d) * HH + h];
        #pragma unroll
        for (int b = 0; b < BS; ++b) {
            float ev = e[b][d];
            accP[b] = fmaf(ev, wp, accP[b]);
            accQ[b] = fmaf(ev, wq, accQ[b]);
        }
    }
    float bb = b1[h];
    #pragma unroll
    for (int b = 0; b < BS; ++b) {
        int idx = ((b * N1) + t) * HH + h;
        P[idx]  = accP[b];
        Qb[idx] = accQ[b] + bb;
        Dd[idx] = accP[b] - accQ[b];
    }
}

// ---------------- Kernel 2: per-triple scores, 16 lanes per (tri,b) task.
// Lane t covers h = t*16 .. t*16+15 -> all row reads fully coalesced.
// Output layout: S[b][tri] (contiguous per-b slab for the DP blocks).
__global__ __launch_bounds__(256) void k_score(
    const float* __restrict__ P, const float* __restrict__ Qb,
    const float* __restrict__ Dd, const float* __restrict__ W2,
    const float* __restrict__ b2, float* __restrict__ S)
{
    int gt = blockIdx.x * 256 + threadIdx.x;
    int task = gt >> 4;
    int t    = gt & 15;
    if (task >= NTASK) return;
    int b   = task / NTRI;
    int tri = task - b * NTRI;

    // decode tri -> (w, i, j') in (w,i,j') enumeration order
    int rem = tri, w = 2;
    while (true) {
        int cnt = (N1 - w) * (w - 1);
        if (rem < cnt) break;
        rem -= cnt; ++w;
    }
    int nj = w - 1;
    int i  = rem / nj;
    int jp = rem - i * nj;
    int j  = i + 1 + jp;
    int k  = i + w;

    const float4* Pr  = (const float4*)(P  + ((b * N1 + i) << 8)) + t * 4;
    const float4* Qr  = (const float4*)(Qb + ((b * N1 + k) << 8)) + t * 4;
    const float4* Dr  = (const float4*)(Dd + ((b * N1 + j) << 8)) + t * 4;
    const float4* W2r = (const float4*)(W2) + t * 8;   // W2[h][2], h = t*16..t*16+15

    float s0 = 0.f, s1 = 0.f;
    #pragma unroll
    for (int q = 0; q < 4; ++q) {
        float4 p = Pr[q], qq = Qr[q], dd = Dr[q];
        float4 wa = W2r[q * 2], wb = W2r[q * 2 + 1];
        float r0 = fmaxf(dd.x + qq.x - p.x, 0.f);
        float r1 = fmaxf(dd.y + qq.y - p.y, 0.f);
        float r2 = fmaxf(dd.z + qq.z - p.z, 0.f);
        float r3 = fmaxf(dd.w + qq.w - p.w, 0.f);
        s0 = fmaf(r0, wa.x, s0); s1 = fmaf(r0, wa.y, s1);
        s0 = fmaf(r1, wa.z, s0); s1 = fmaf(r1, wa.w, s1);
        s0 = fmaf(r2, wb.x, s0); s1 = fmaf(r2, wb.y, s1);
        s0 = fmaf(r3, wb.z, s0); s1 = fmaf(r3, wb.w, s1);
    }
    #pragma unroll
    for (int d = 1; d < 16; d <<= 1) {
        s0 += __shfl_xor(s0, d);
        s1 += __shfl_xor(s1, d);
    }
    if (t == 0) {
        float S0 = s0 + b2[0], S1 = s1 + b2[1];
        S[b * NTRI + tri] = fmaxf(S0, S1) + log1pf(__expf(-fabsf(S0 - S1)));
    }
}

// ---------------- Kernel 3: per-batch DP, 8 blocks x 4 waves (256 threads)
// B packed upper-triangular per b: cell (i,j), j>i, at tri_base(i) + (j-i-1).
__device__ __forceinline__ int tri_base(int i) { return (i * (81 - i)) >> 1; }
#define BIDX(i, j) (tri_base(i) + ((j) - (i) - 1))

// per-b element offset of step-W's S chunk, (w,i,j') enumeration
constexpr int soff(int W) {
    int s = 0;
    for (int v = 2; v < W; ++v) s += (N1 - v) * (v - 1);
    return s;
}
// lanes per cell: pow2, m*T <= 256, T <= 16, T < 2*nj
// -> local CH <= 4, butterfly rounds <= 4, cells never straddle a wave
constexpr int pick_T(int m, int nj) {
    int T = 1;
    while (T < 16 && m * (T * 2) <= DPB && T < nj) T *= 2;
    return T;
}

template<int W>
__device__ __forceinline__ void dp_step(float* __restrict__ Btri,
                                        const float* __restrict__ Sl, int tid)
{
    constexpr int m    = N1 - W;
    constexpr int nj   = W - 1;
    constexpr int T    = pick_T(m, nj);
    constexpr int CH   = (nj + T - 1) / T;
    constexpr int base = soff(W);

    if (tid < m * T) {
        const int i = tid / T;
        const int h = tid % T;
        const int k = i + W;

        float g[CH];
        #pragma unroll
        for (int q = 0; q < CH; ++q) {
            int jp = h + q * T;                        // strided: lanes -> consecutive addrs
            bool live = (q < CH - 1) || (jp < nj);     // compile-time true except last q
            int jj = live ? jp : 0;
            float v = Sl[base + i * nj + jj]
                    + Btri[BIDX(i, i + 1 + jj)]
                    + Btri[BIDX(i + 1 + jj, k)];
            g[q] = live ? v : MNEG;
        }
        // local tree LSE (<=4 elements)
        float mx = g[0];
        #pragma unroll
        for (int q = 1; q < CH; ++q) mx = fmaxf(mx, g[q]);
        float s = 0.f;
        #pragma unroll
        for (int q = 0; q < CH; ++q) s += __expf(g[q] - mx);
        // in-wave fused online-LSE butterfly over T lanes (<=4 rounds).
        // Fully-dead lanes (mx==MNEG) are annihilated: exp(MNEG - real) == 0,
        // and lane h==0 is always live.
        #pragma unroll
        for (int d = 1; d < T; d <<= 1) {
            float mo = __shfl_xor(mx, d);
            float so = __shfl_xor(s, d);
            float nm = fmaxf(mx, mo);
            s = s * __expf(mx - nm) + so * __expf(mo - nm);
            mx = nm;
        }
        if (h == 0)
            Btri[BIDX(i, k)] = mx + __logf(s);   // width-W entry: never read at step W
    }
    __syncthreads();   // one 4-wave barrier per step
}

template<int W>
__device__ __forceinline__ void dp_from(float* __restrict__ Btri,
                                        const float* __restrict__ Sl, int tid)
{
    dp_step<W>(Btri, Sl, tid);
    if constexpr (W + 1 <= N_TOK) dp_from<W + 1>(Btri, Sl, tid);
}

__global__ __launch_bounds__(DPB) void k_dp(
    const float* __restrict__ Sg, const int* __restrict__ lengths,
    float* __restrict__ out)
{
    __shared__ __align__(16) float Sl[NTRI];   // 42640 B: this b's full S
    __shared__ float Btri[820];                // 3280 B: this b's triangle
    const int tid = threadIdx.x;
    const int b   = blockIdx.x;

    // stage all of S[b]: NTRI/4 = 2665 float4s (exact), 16B-aligned per b
    const float4* src = (const float4*)(Sg + b * NTRI);
    float4* dst = (float4*)Sl;
    for (int x = tid; x < NTRI / 4; x += DPB) dst[x] = src[x];
    // width-1 diagonal = 0 (only read entries not computed in the loop)
    if (tid < N_TOK) Btri[tri_base(tid)] = 0.f;
    __syncthreads();

    dp_from<2>(Btri, Sl, tid);

    if (tid == 0) {
        int L = lengths[b];
        out[b] = Btri[BIDX(0, L)];
    }
}

extern "C" void kernel_launch(void* const* d_in, const int* in_sizes, int n_in,
                              void* d_out, int out_size, void* d_ws, size_t ws_size,
                              hipStream_t stream)
{
    const float* enc = (const float*)d_in[0];
    const float* W1  = (const float*)d_in[1];
    const float* b1  = (const float*)d_in[2];
    const float* W2  = (const float*)d_in[3];
    const float* b2  = (const float*)d_in[4];
    const int* lengths = (const int*)d_in[5];

    float* ws = (float*)d_ws;
    float* P  = ws;
    float* Qb = ws + ROWF;
    float* Dd = ws + 2 * ROWF;
    float* S  = ws + 3 * ROWF;   // NTASK floats; total ws use ~1.35 MB

    k_proj<<<dim3(N1), dim3(256), 0, stream>>>(enc, W1, b1, P, Qb, Dd);
    k_score<<<dim3((NTASK * 16 + 255) / 256), dim3(256), 0, stream>>>(P, Qb, Dd, W2, b2, S);
    k_dp<<<dim3(BS), dim3(DPB), 0, stream>>>(S, lengths, (float*)d_out);
}